// Round 3
// baseline (399.782 us; speedup 1.0000x reference)
//
#include <hip/hip_runtime.h>

#define NB 16
#define CHN 64
#define NPIX 4096   // 64*64
#define MPOOL 1024  // 32*32
#define LOG2E 1.44269504088896f

// -------------------------------------------------------------------------
// Kernel 1: fused 1x1 convs (theta, phi, g) + 2x2 maxpool of phi and g.
// grid: NB*32 blocks (block = 2 image rows = 128 px), 512 threads
// (128 px x 4 output-channel groups of 12). x re-reads across groups hit L1.
// -------------------------------------------------------------------------
__global__ __launch_bounds__(512) void proj_pool_kernel(
    const float* __restrict__ x,     // [B][64][4096]
    const float* __restrict__ Wth,   // [8][64]
    const float* __restrict__ Wph,   // [8][64]
    const float* __restrict__ Wg,    // [32][64]
    float* __restrict__ theta,       // [B][8][4096]
    float* __restrict__ phi,         // [B][8][1024]  (pooled)
    float* __restrict__ g)           // [B][32][1024] (pooled)
{
    __shared__ float wT[64][48];     // wT[c][o]
    __shared__ float pg[40][128];    // per-pixel phi(0-7)/g(8-39)

    const int t  = threadIdx.x;
    const int b  = blockIdx.x >> 5;
    const int rp = blockIdx.x & 31;  // row-pair (2 image rows)
    const int n0 = rp * 128;
    const int px = t & 127;
    const int gi = t >> 7;           // output-channel group 0..3
    const int ob = gi * 12;

    for (int i = t; i < 3072; i += 512) {
        const int o = i >> 6, c = i & 63;
        float v;
        if (o < 8)       v = Wth[o * 64 + c];
        else if (o < 16) v = Wph[(o - 8) * 64 + c];
        else             v = Wg[(o - 16) * 64 + c];
        wT[c][o] = v;
    }
    __syncthreads();

    float acc[12];
    #pragma unroll
    for (int j = 0; j < 12; ++j) acc[j] = 0.0f;

    const float* xb = x + (size_t)b * CHN * NPIX + n0 + px;
    #pragma unroll 8
    for (int c = 0; c < 64; ++c) {
        const float xc = xb[c * NPIX];
        const float4* w4 = (const float4*)&wT[c][ob];   // 48B-aligned per group
        const float4 w0 = w4[0], w1 = w4[1], w2 = w4[2];
        acc[0] += w0.x * xc; acc[1] += w0.y * xc; acc[2]  += w0.z * xc; acc[3]  += w0.w * xc;
        acc[4] += w1.x * xc; acc[5] += w1.y * xc; acc[6]  += w1.z * xc; acc[7]  += w1.w * xc;
        acc[8] += w2.x * xc; acc[9] += w2.y * xc; acc[10] += w2.z * xc; acc[11] += w2.w * xc;
    }

    // theta straight to global; phi/g per-pixel values to LDS (contiguous px).
    #pragma unroll
    for (int j = 0; j < 12; ++j) {
        const int o = ob + j;
        if (o < 8) theta[((size_t)b * 8 + o) * NPIX + n0 + px] = acc[j];
        else       pg[o - 8][px] = acc[j];
    }
    __syncthreads();

    // Pool: 40 ch x 32 pooled cols (1 pooled row per block).
    for (int i = t; i < 1280; i += 512) {
        const int chn = i >> 5, pc = i & 31;
        const float v0 = pg[chn][2 * pc];
        const float v1 = pg[chn][2 * pc + 1];
        const float v2 = pg[chn][64 + 2 * pc];
        const float v3 = pg[chn][65 + 2 * pc];
        const float mx = fmaxf(fmaxf(v0, v1), fmaxf(v2, v3));
        const int m = rp * 32 + pc;
        if (chn < 8) phi[((size_t)b * 8 + chn) * MPOOL + m] = mx;
        else         g[((size_t)b * 32 + (chn - 8)) * MPOOL + m] = mx;
    }
}

// -------------------------------------------------------------------------
// Kernel 2: fused attention + W_o + residual, key-split for occupancy.
// grid: NB*64 blocks (block = 64 queries), 256 threads = 64 q x 4 key-groups.
// Group kt handles keys [kt*256, kt*256+256) in 4 chunks of 64; partials
// tree-reduced through LDS. LDS layout matches global (c-major, key-fast):
// staging writes contiguous, compute reads wave-uniform broadcast -> no
// bank conflicts anywhere.
// -------------------------------------------------------------------------
__global__ __launch_bounds__(256) void attn_kernel(
    const float* __restrict__ x,      // [B][64][4096]
    const float* __restrict__ theta,  // [B][8][4096]
    const float* __restrict__ phi,    // [B][8][1024]
    const float* __restrict__ g,      // [B][32][1024]
    const float* __restrict__ Wo,     // [64][32]
    const float* __restrict__ gammap,
    float* __restrict__ out)          // [B][64][4096]
{
    __shared__ float smem[10496];   // staging [4][8][64]+[4][32][64] | red [4][64][33] + avn [32][64]
    __shared__ float wo_lds[2048];  // [64][32]

    const int t  = threadIdx.x;
    const int b  = blockIdx.x >> 6;
    const int qt = blockIdx.x & 63;
    const int n0 = qt * 64;
    const int q  = t & 63;
    const int kt = t >> 6;          // key-group = wave id

    for (int i = t; i < 2048; i += 256) wo_lds[i] = Wo[i];

    float th[8];
    #pragma unroll
    for (int c = 0; c < 8; ++c)
        th[c] = theta[((size_t)b * 8 + c) * NPIX + n0 + q] * LOG2E;

    float av[32];
    #pragma unroll
    for (int c = 0; c < 32; ++c) av[c] = 0.0f;
    float l = 0.0f;

    float* phi_s = smem;            // [grp][c][key]  4*8*64
    float* g_s   = smem + 2048;     // [grp][c][key]  4*32*64

    for (int ck = 0; ck < 4; ++ck) {
        __syncthreads();
        // stage phi slices for all 4 groups (float4, fully coalesced)
        for (int i = t; i < 512; i += 256) {
            const int flat = i * 4;
            const int grp = flat >> 9, c = (flat >> 6) & 7, k = flat & 63;
            const float4 v = *(const float4*)(phi + (((size_t)b * 8 + c) << 10)
                                              + grp * 256 + ck * 64 + k);
            *(float4*)&phi_s[(grp * 8 + c) * 64 + k] = v;
        }
        // stage g slices
        for (int i = t; i < 2048; i += 256) {
            const int flat = i * 4;
            const int grp = flat >> 11, c = (flat >> 6) & 31, k = flat & 63;
            const float4 v = *(const float4*)(g + (((size_t)b * 32 + c) << 10)
                                              + grp * 256 + ck * 64 + k);
            *(float4*)&g_s[(grp * 32 + c) * 64 + k] = v;
        }
        __syncthreads();

        const float* ps = phi_s + kt * 512;
        const float* gs = g_s + kt * 2048;
        #pragma unroll
        for (int k8 = 0; k8 < 8; ++k8) {
            const int k0 = k8 * 8;
            float s0 = 0, s1 = 0, s2 = 0, s3 = 0, s4 = 0, s5 = 0, s6 = 0, s7 = 0;
            #pragma unroll
            for (int c = 0; c < 8; ++c) {
                const float4 a  = *(const float4*)&ps[c * 64 + k0];
                const float4 bb = *(const float4*)&ps[c * 64 + k0 + 4];
                s0 += th[c] * a.x;  s1 += th[c] * a.y;
                s2 += th[c] * a.z;  s3 += th[c] * a.w;
                s4 += th[c] * bb.x; s5 += th[c] * bb.y;
                s6 += th[c] * bb.z; s7 += th[c] * bb.w;
            }
            const float p0 = __builtin_exp2f(s0), p1 = __builtin_exp2f(s1);
            const float p2 = __builtin_exp2f(s2), p3 = __builtin_exp2f(s3);
            const float p4 = __builtin_exp2f(s4), p5 = __builtin_exp2f(s5);
            const float p6 = __builtin_exp2f(s6), p7 = __builtin_exp2f(s7);
            l += ((p0 + p1) + (p2 + p3)) + ((p4 + p5) + (p6 + p7));
            #pragma unroll
            for (int c = 0; c < 32; ++c) {
                const float4 g0 = *(const float4*)&gs[c * 64 + k0];
                const float4 g1 = *(const float4*)&gs[c * 64 + k0 + 4];
                av[c] += p0 * g0.x + p1 * g0.y + p2 * g0.z + p3 * g0.w
                       + p4 * g1.x + p5 * g1.y + p6 * g1.z + p7 * g1.w;
            }
        }
    }

    // tree-reduce partials (av, l) across the 4 key-groups through LDS
    __syncthreads();
    float* red = smem;              // [kt][q][33]
    #pragma unroll
    for (int c = 0; c < 32; ++c) red[kt * 2112 + q * 33 + c] = av[c];
    red[kt * 2112 + q * 33 + 32] = l;
    __syncthreads();

    float* avn = smem + 8448;       // [c][q] 32*64
    {
        const int q2 = t & 63, cb = (t >> 6) * 8;
        const float lt = red[q2 * 33 + 32] + red[2112 + q2 * 33 + 32]
                       + red[4224 + q2 * 33 + 32] + red[6336 + q2 * 33 + 32];
        const float rinv = 1.0f / lt;
        #pragma unroll
        for (int j = 0; j < 8; ++j) {
            const int c = cb + j;
            const float v = red[q2 * 33 + c] + red[2112 + q2 * 33 + c]
                          + red[4224 + q2 * 33 + c] + red[6336 + q2 * 33 + c];
            avn[c * 64 + q2] = v * rinv;
        }
    }
    __syncthreads();

    // epilogue: W_o + residual. 64 q x 4 oc-groups of 16.
    const int q3 = t & 63, ocb = (t >> 6) * 16;
    float avf[32];
    #pragma unroll
    for (int c = 0; c < 32; ++c) avf[c] = avn[c * 64 + q3];
    const float gamma = *gammap;
    const float* xb = x + (size_t)b * CHN * NPIX + n0 + q3;
    float* obp = out + (size_t)b * CHN * NPIX + n0 + q3;
    #pragma unroll 4
    for (int j = 0; j < 16; ++j) {
        const int oc = ocb + j;
        const float4* wv = (const float4*)&wo_lds[oc * 32];
        float o = 0.0f;
        #pragma unroll
        for (int jj = 0; jj < 8; ++jj) {
            const float4 w = wv[jj];
            o += w.x * avf[4 * jj + 0] + w.y * avf[4 * jj + 1]
               + w.z * avf[4 * jj + 2] + w.w * avf[4 * jj + 3];
        }
        obp[oc * NPIX] = gamma * o + xb[oc * NPIX];
    }
}

extern "C" void kernel_launch(void* const* d_in, const int* in_sizes, int n_in,
                              void* d_out, int out_size, void* d_ws, size_t ws_size,
                              hipStream_t stream) {
    const float* x     = (const float*)d_in[0];
    const float* Wth   = (const float*)d_in[1];
    const float* Wph   = (const float*)d_in[2];
    const float* Wg    = (const float*)d_in[3];
    const float* Wo    = (const float*)d_in[4];
    const float* gamma = (const float*)d_in[5];
    float* out = (float*)d_out;

    float* theta = (float*)d_ws;                       // 16*8*4096
    float* phi   = theta + (size_t)NB * 8 * NPIX;      // 16*8*1024
    float* g     = phi   + (size_t)NB * 8 * MPOOL;     // 16*32*1024

    proj_pool_kernel<<<NB * 32, 512, 0, stream>>>(x, Wth, Wph, Wg, theta, phi, g);
    attn_kernel<<<NB * 64, 256, 0, stream>>>(x, theta, phi, g, Wo, gamma, out);
}

// Round 4
// 109.493 us; speedup vs baseline: 3.6512x; 3.6512x over previous
//
#include <hip/hip_runtime.h>

typedef unsigned int uint;
typedef unsigned short ushort;
typedef __attribute__((ext_vector_type(8))) short bf16x8;
typedef __attribute__((ext_vector_type(16))) float f32x16;

#define LOG2E 1.44269504088896f
#define NB 16
#define NPIX 4096   // 64*64 pixels per image
#define MKEY 1024   // pooled keys per image

// ---- helpers -------------------------------------------------------------
__device__ inline uint cvtpk(float lo, float hi) {   // pack 2 f32 -> bf16x2 (RNE)
    uint r;
    asm("v_cvt_pk_bf16_f32 %0, %1, %2" : "=v"(r) : "v"(lo), "v"(hi));
    return r;
}
union U4B8 { uint u[4]; bf16x8 b; };
__device__ inline f32x16 zero16() {
    f32x16 z;
#pragma unroll
    for (int i = 0; i < 16; ++i) z[i] = 0.0f;
    return z;
}

// ws layout: thetaT bf16 [16][4096][8]  (524288 ushort)
//            per-b kv    [16] x { phiT bf16 [1024][8] (8192 us) |
//                                 g_frag bf16 [64 T][64 lane][8 j] (32768 us) }
// g_frag: element g[b][gc][key] lives at T=key>>4, lane=((key>>3)&1)*32+gc, j=key&7
// (exactly the mfma_32x32x16 B-operand order: B[k=8h+j][col=gc]).

// -------------------------------------------------------------------------
// Kernel 1: MFMA projections + 2x2 maxpool.
// grid 512 = 16 b x 32 row-pairs; 256 thr = 4 waves x 32 px.
// Out-channels: 0-7 theta (pre-scaled by log2e), 8-15 phi, 16-47 g.
// Wave computes D[oc, px] = W[oc, c] * x[c, px] via 2 oc-tiles x 4 k-slots.
// -------------------------------------------------------------------------
__global__ __launch_bounds__(256) void proj_kernel(
    const float* __restrict__ x,   const float* __restrict__ Wth,
    const float* __restrict__ Wph, const float* __restrict__ Wg,
    ushort* __restrict__ thetaT,   ushort* __restrict__ kv)
{
    __shared__ float pool_s[40][128];   // phi(0-7)/g(8-39) per-pixel values

    const int t  = threadIdx.x;
    const int w  = t >> 6, l = t & 63, ql = l & 31, h = l >> 5;
    const int b  = blockIdx.x >> 5, rp = blockIdx.x & 31;
    const int pxb = w*32 + ql;          // 0..127 within 2 image rows
    const int n   = rp*128 + pxb;       // global pixel

    // A-frags: weights (lane = oc row, k = 16s+8h+j)
    bf16x8 wA[2][4];
#pragma unroll
    for (int T = 0; T < 2; ++T) {
        const int row = T*32 + ql;
        const float* wsrc = nullptr; float scale = 1.0f;
        if (row < 8)       { wsrc = Wth + row*64; scale = LOG2E; }
        else if (row < 16) { wsrc = Wph + (row-8)*64; }
        else if (row < 48) { wsrc = Wg  + (row-16)*64; }
#pragma unroll
        for (int s = 0; s < 4; ++s) {
            float v[8];
            if (wsrc) {
                const float* p = wsrc + s*16 + h*8;
#pragma unroll
                for (int j = 0; j < 8; ++j) v[j] = p[j] * scale;
            } else {
#pragma unroll
                for (int j = 0; j < 8; ++j) v[j] = 0.0f;
            }
            U4B8 cv;
            cv.u[0] = cvtpk(v[0],v[1]); cv.u[1] = cvtpk(v[2],v[3]);
            cv.u[2] = cvtpk(v[4],v[5]); cv.u[3] = cvtpk(v[6],v[7]);
            wA[T][s] = cv.b;
        }
    }

    // B-frags from global x (coalesced per-j dword loads) + MFMA
    const float* xb = x + (size_t)b*64*NPIX + n;
    f32x16 c0 = zero16(), c1 = zero16();
#pragma unroll
    for (int s = 0; s < 4; ++s) {
        float v[8];
#pragma unroll
        for (int j = 0; j < 8; ++j) v[j] = xb[(size_t)(s*16 + h*8 + j) * NPIX];
        U4B8 cv;
        cv.u[0] = cvtpk(v[0],v[1]); cv.u[1] = cvtpk(v[2],v[3]);
        cv.u[2] = cvtpk(v[4],v[5]); cv.u[3] = cvtpk(v[6],v[7]);
        c0 = __builtin_amdgcn_mfma_f32_32x32x16_bf16(wA[0][s], cv.b, c0, 0,0,0);
        c1 = __builtin_amdgcn_mfma_f32_32x32x16_bf16(wA[1][s], cv.b, c1, 0,0,0);
    }

    // theta (rows 0-7): straight to global, bf16, c = 4h + {0..3}
    {
        const uint t01 = cvtpk(c0[0], c0[1]);
        const uint t23 = cvtpk(c0[2], c0[3]);
        uint2 tv; tv.x = t01; tv.y = t23;
        *(uint2*)(thetaT + ((size_t)(b*NPIX + n))*8 + 4*h) = tv;
    }
    // phi/g pre-pool values -> LDS. pool row = crow-8 (tile0), 24+crow (tile1)
#pragma unroll
    for (int r = 4; r < 16; ++r) {
        const int crow = (r&3) + 8*(r>>2) + 4*h;    // 8..31
        pool_s[crow - 8][pxb] = c0[r];
    }
#pragma unroll
    for (int r = 0; r < 8; ++r) {
        const int crow = (r&3) + 8*(r>>2) + 4*h;    // 0..15 -> gc 16..31
        pool_s[24 + crow][pxb] = c1[r];
    }
    __syncthreads();

    // 2x2 maxpool (rows of this row-pair) + scatter to phiT / g_frag
    ushort* kvb = kv + (size_t)b * 40960;
    for (int i = t; i < 1280; i += 256) {
        const int ch = i >> 5, mc = i & 31;
        const float m0 = pool_s[ch][2*mc],    m1 = pool_s[ch][2*mc+1];
        const float m2 = pool_s[ch][64+2*mc], m3 = pool_s[ch][65+2*mc];
        const float mx = fmaxf(fmaxf(m0,m1), fmaxf(m2,m3));
        const ushort bv = (ushort)(cvtpk(mx, mx) & 0xFFFFu);
        const int key = rp*32 + mc;
        if (ch < 8) {
            kvb[key*8 + ch] = bv;                               // phiT[key][c]
        } else {
            const int gc = ch - 8;
            kvb[8192 + ((size_t)((key>>4)*64 + ((key>>3)&1)*32 + gc))*8 + (key&7)] = bv;
        }
    }
}

// -------------------------------------------------------------------------
// Kernel 2: flash attention (swapped QK^T) + W_o + residual, all MFMA.
// grid 256 = 16 b x 16 q-tiles; 512 thr = 8 waves x 32 q.
// Keys staged in 2 halves of 512 (40 KB LDS); epilogue aliases LDS for the
// av transpose. S^T = mfma(K,Q) puts P[key-regs][q-lane]; in-register exp +
// row-sum; cvt_pk + shfl_xor(32) re-bucketing builds the PV A-fragment.
// -------------------------------------------------------------------------
__global__ __launch_bounds__(512) void attn_kernel(
    const float* __restrict__ x,  const ushort* __restrict__ thetaT,
    const ushort* __restrict__ kv, const float* __restrict__ Wo,
    const float* __restrict__ gammap, float* __restrict__ out)
{
    __shared__ __align__(16) char smem[40960];
    ushort* phiT_s  = (ushort*)smem;            // 8 KB   [512 key][8 c]
    ushort* gfrag_s = (ushort*)(smem + 8192);   // 32 KB  [32 T][64 lane][8 j]

    const int t  = threadIdx.x;
    const int w  = t >> 6, l = t & 63, ql = l & 31, h = l >> 5;
    const int b  = blockIdx.x >> 4, qt = blockIdx.x & 15;
    const int nq = qt*256 + w*32 + ql;          // this lane's query pixel
    const ushort* kvb = kv + (size_t)b * 40960;

    // Q fragment (B-operand): c 0-7 real, c 8-15 zero
    bf16x8 qf;
    { U4B8 z; z.u[0]=z.u[1]=z.u[2]=z.u[3]=0;
      if (h == 0) qf = *(const bf16x8*)(thetaT + ((size_t)(b*NPIX + nq))*8);
      else        qf = z.b; }

    f32x16 acc = zero16();
    float lp = 0.0f;

    for (int H = 0; H < 2; ++H) {
        __syncthreads();
        {   // stage 512 keys: phiT half (8 KB) + g_frag half (32 KB)
            const uint4* sp = (const uint4*)(kvb + H*4096);
            ((uint4*)phiT_s)[t] = sp[t];
            const uint4* sg = (const uint4*)(kvb + 8192 + H*16384);
            uint4* dg = (uint4*)gfrag_s;
#pragma unroll
            for (int i = 0; i < 4; ++i) dg[t + i*512] = sg[t + i*512];
        }
        __syncthreads();

        for (int kt = 0; kt < 16; ++kt) {       // 32 keys per iter
            bf16x8 af;
            { U4B8 z; z.u[0]=z.u[1]=z.u[2]=z.u[3]=0;
              if (h == 0) af = *(const bf16x8*)(phiT_s + (kt*32 + ql)*8);
              else        af = z.b; }
            // S^T[key, q]
            f32x16 st = __builtin_amdgcn_mfma_f32_32x32x16_bf16(af, qf, zero16(), 0,0,0);
            f32x16 P;
#pragma unroll
            for (int r = 0; r < 16; ++r) P[r] = __builtin_exp2f(st[r]);
            lp += (((P[0]+P[1])+(P[2]+P[3])) + ((P[4]+P[5])+(P[6]+P[7])))
                + (((P[8]+P[9])+(P[10]+P[11])) + ((P[12]+P[13])+(P[14]+P[15])));
#pragma unroll
            for (int ks = 0; ks < 2; ++ks) {
                const int base = ks*8;
                // own keys (reg r, half h): key = (r&3) + 8*((r>>2)&1) + 16*(r>>3) + 4h
                const uint X01 = cvtpk(P[base+0], P[base+1]);
                const uint X23 = cvtpk(P[base+2], P[base+3]);
                const uint Y01 = cvtpk(P[base+4], P[base+5]);
                const uint Y23 = cvtpk(P[base+6], P[base+7]);
                const uint sX01 = (uint)__shfl_xor((int)X01, 32, 64);
                const uint sX23 = (uint)__shfl_xor((int)X23, 32, 64);
                const uint sY01 = (uint)__shfl_xor((int)Y01, 32, 64);
                const uint sY23 = (uint)__shfl_xor((int)Y23, 32, 64);
                U4B8 pa;                         // A[q=lane&31][k=8h+j]
                pa.u[0] = h ? sY01 : X01;
                pa.u[1] = h ? sY23 : X23;
                pa.u[2] = h ? Y01  : sX01;
                pa.u[3] = h ? Y23  : sX23;
                const bf16x8 gB = *(const bf16x8*)(gfrag_s + ((kt*2 + ks)*64 + l)*8);
                acc = __builtin_amdgcn_mfma_f32_32x32x16_bf16(pa.b, gB, acc, 0,0,0);
            }
        }
    }

    // softmax denominator for this lane's q = ql (both halves combined)
    const float ltot = lp + __shfl_xor(lp, 32, 64);
    const float rinv = 1.0f / ltot;

    // transpose av through LDS (aliases staging buffers; all K-loop reads done)
    __syncthreads();
    float* avw = (float*)smem + w * (32*33);
#pragma unroll
    for (int r = 0; r < 16; ++r) {
        const int crow = (r&3) + 8*(r>>2) + 4*h;     // q row
        avw[crow*33 + ql] = acc[r];                  // [q][gc]
    }
    __syncthreads();

    // epilogue: o^T[oc, q] = Wo[oc, gc] x (av[ q, gc]/l)
    bf16x8 avB[2];
#pragma unroll
    for (int s = 0; s < 2; ++s) {
        float v[8];
#pragma unroll
        for (int j = 0; j < 8; ++j) v[j] = avw[ql*33 + s*16 + h*8 + j] * rinv;
        U4B8 cv;
        cv.u[0]=cvtpk(v[0],v[1]); cv.u[1]=cvtpk(v[2],v[3]);
        cv.u[2]=cvtpk(v[4],v[5]); cv.u[3]=cvtpk(v[6],v[7]);
        avB[s] = cv.b;
    }
    const float gamma = gammap[0];
    const float* xb = x  + (size_t)b*64*NPIX + nq;
    float*       ob = out + (size_t)b*64*NPIX + nq;
#pragma unroll
    for (int T = 0; T < 2; ++T) {
        f32x16 oacc = zero16();
#pragma unroll
        for (int s = 0; s < 2; ++s) {
            const float* wrow = Wo + (T*32 + ql)*32 + s*16 + h*8;
            float v[8];
#pragma unroll
            for (int j = 0; j < 8; ++j) v[j] = wrow[j];
            U4B8 cv;
            cv.u[0]=cvtpk(v[0],v[1]); cv.u[1]=cvtpk(v[2],v[3]);
            cv.u[2]=cvtpk(v[4],v[5]); cv.u[3]=cvtpk(v[6],v[7]);
            oacc = __builtin_amdgcn_mfma_f32_32x32x16_bf16(cv.b, avB[s], oacc, 0,0,0);
        }
#pragma unroll
        for (int r = 0; r < 16; ++r) {
            const int oc = T*32 + (r&3) + 8*(r>>2) + 4*h;
            ob[(size_t)oc*NPIX] = gamma * oacc[r] + xb[(size_t)oc*NPIX];
        }
    }
}

extern "C" void kernel_launch(void* const* d_in, const int* in_sizes, int n_in,
                              void* d_out, int out_size, void* d_ws, size_t ws_size,
                              hipStream_t stream) {
    const float* x     = (const float*)d_in[0];
    const float* Wth   = (const float*)d_in[1];
    const float* Wph   = (const float*)d_in[2];
    const float* Wg    = (const float*)d_in[3];
    const float* Wo    = (const float*)d_in[4];
    const float* gamma = (const float*)d_in[5];
    float* out = (float*)d_out;

    ushort* thetaT = (ushort*)d_ws;          // 16*4096*8 ushort = 1 MB
    ushort* kv     = thetaT + (size_t)NB*NPIX*8;   // 16 * 40960 ushort

    proj_kernel<<<NB*32, 256, 0, stream>>>(x, Wth, Wph, Wg, thetaT, kv);
    attn_kernel<<<NB*16, 512, 0, stream>>>(x, thetaT, kv, Wo, gamma, out);
}

// Round 5
// 106.551 us; speedup vs baseline: 3.7520x; 1.0276x over previous
//
#include <hip/hip_runtime.h>

typedef unsigned int uint;
typedef unsigned short ushort;
typedef __attribute__((ext_vector_type(8))) short bf16x8;
typedef __attribute__((ext_vector_type(16))) float f32x16;

#define LOG2E 1.44269504088896f
#define NB 16
#define NPIX 4096   // 64*64 pixels per image
#define MKEY 1024   // pooled keys per image

// ---- helpers -------------------------------------------------------------
__device__ inline uint cvtpk(float lo, float hi) {   // pack 2 f32 -> bf16x2 (RNE)
    uint r;
    asm("v_cvt_pk_bf16_f32 %0, %1, %2" : "=v"(r) : "v"(lo), "v"(hi));
    return r;
}
union U4B8 { uint u[4]; bf16x8 b; };
__device__ inline f32x16 zero16() {
    f32x16 z;
#pragma unroll
    for (int i = 0; i < 16; ++i) z[i] = 0.0f;
    return z;
}

// ws layout: thetaT bf16 [16][4096][8]  (524288 ushort)
//            per-b kv    [16] x { phiT bf16 [1024][8] (8192 us) |
//                                 g_frag bf16 [64 T][64 lane][8 j] (32768 us) }
// g_frag: element g[b][gc][key] at T=key>>4, lane=((key>>3)&1)*32+gc, j=key&7
// (the mfma_32x32x16 B-operand order).

// -------------------------------------------------------------------------
// Kernel 1: MFMA projections + 2x2 maxpool.
// grid 512 = 16 b x 32 row-pairs; 256 thr = 4 waves x 32 px.
// Weights staged coalesced into LDS (fixes 256B-stride per-lane gathers);
// all 32 x-loads issued before any pack/MFMA (latency batching).
// -------------------------------------------------------------------------
__global__ __launch_bounds__(256, 4) void proj_kernel(
    const float* __restrict__ x,   const float* __restrict__ Wth,
    const float* __restrict__ Wph, const float* __restrict__ Wg,
    ushort* __restrict__ thetaT,   ushort* __restrict__ kv)
{
    __shared__ float wTs[64][66];       // [oc][c], +2 pad: 2-way max on reads
    __shared__ float pool_s[40][128];   // phi(0-7)/g(8-39) per-pixel values

    const int t  = threadIdx.x;
    const int w  = t >> 6, l = t & 63, ql = l & 31, h = l >> 5;
    const int b  = blockIdx.x >> 5, rp = blockIdx.x & 31;
    const int pxb = w*32 + ql;          // 0..127 within 2 image rows
    const int n   = rp*128 + pxb;       // global pixel

    // coalesced weight staging (theta rows pre-scaled by log2e); rows 48-63 = 0
    for (int i = t; i < 4096; i += 256) {
        const int o = i >> 6, c = i & 63;
        float v;
        if (o < 8)       v = Wth[i] * LOG2E;
        else if (o < 16) v = Wph[i - 512];
        else if (o < 48) v = Wg[i - 1024];
        else             v = 0.0f;
        wTs[o][c] = v;
    }

    // issue all 32 x loads up front (independent, coalesced across lanes)
    const float* xb = x + (size_t)b*64*NPIX + n;
    float xv[32];
#pragma unroll
    for (int k = 0; k < 32; ++k) {
        const int s = k >> 3, j = k & 7;
        xv[k] = xb[(size_t)(s*16 + h*8 + j) * NPIX];
    }
    __syncthreads();

    // A-frags (weights) from LDS: lane = oc row, k = 16s+8h+j
    bf16x8 wA[2][4];
#pragma unroll
    for (int T = 0; T < 2; ++T)
#pragma unroll
        for (int s = 0; s < 4; ++s) {
            const float* p = &wTs[T*32 + ql][s*16 + h*8];
            U4B8 cv;
            cv.u[0] = cvtpk(p[0],p[1]); cv.u[1] = cvtpk(p[2],p[3]);
            cv.u[2] = cvtpk(p[4],p[5]); cv.u[3] = cvtpk(p[6],p[7]);
            wA[T][s] = cv.b;
        }

    f32x16 c0 = zero16(), c1 = zero16();
#pragma unroll
    for (int s = 0; s < 4; ++s) {
        U4B8 cv;
        cv.u[0] = cvtpk(xv[s*8+0],xv[s*8+1]); cv.u[1] = cvtpk(xv[s*8+2],xv[s*8+3]);
        cv.u[2] = cvtpk(xv[s*8+4],xv[s*8+5]); cv.u[3] = cvtpk(xv[s*8+6],xv[s*8+7]);
        c0 = __builtin_amdgcn_mfma_f32_32x32x16_bf16(wA[0][s], cv.b, c0, 0,0,0);
        c1 = __builtin_amdgcn_mfma_f32_32x32x16_bf16(wA[1][s], cv.b, c1, 0,0,0);
    }

    // theta (rows 0-7): straight to global, bf16
    {
        uint2 tv;
        tv.x = cvtpk(c0[0], c0[1]);
        tv.y = cvtpk(c0[2], c0[3]);
        *(uint2*)(thetaT + ((size_t)(b*NPIX + n))*8 + 4*h) = tv;
    }
    // phi/g pre-pool values -> LDS
#pragma unroll
    for (int r = 4; r < 16; ++r) {
        const int crow = (r&3) + 8*(r>>2) + 4*h;    // 8..31
        pool_s[crow - 8][pxb] = c0[r];
    }
#pragma unroll
    for (int r = 0; r < 8; ++r) {
        const int crow = (r&3) + 8*(r>>2) + 4*h;    // 0..15 -> gc 16..31
        pool_s[24 + crow][pxb] = c1[r];
    }
    __syncthreads();

    // 2x2 maxpool: each item covers TWO adjacent pooled cols -> paired stores
    ushort* kvb = kv + (size_t)b * 40960;
    for (int i = t; i < 640; i += 256) {
        const int ch = i >> 4, mp = i & 15;
        const int cp = 4*mp;
        const float m0 = fmaxf(fmaxf(pool_s[ch][cp],   pool_s[ch][cp+1]),
                               fmaxf(pool_s[ch][64+cp], pool_s[ch][65+cp]));
        const float m1 = fmaxf(fmaxf(pool_s[ch][cp+2], pool_s[ch][cp+3]),
                               fmaxf(pool_s[ch][66+cp], pool_s[ch][67+cp]));
        const uint pk = cvtpk(m0, m1);
        const int key0 = rp*32 + 2*mp;
        if (ch < 8) {
            kvb[key0*8 + ch]     = (ushort)(pk & 0xFFFFu);
            kvb[(key0+1)*8 + ch] = (ushort)(pk >> 16);
        } else {
            const int gc = ch - 8;
            const int base = ((key0>>4)*64 + ((key0>>3)&1)*32 + gc)*8 + (key0&7);
            *(uint*)(kvb + 8192 + base) = pk;   // two keys, one dword
        }
    }
}

// -------------------------------------------------------------------------
// Kernel 2: flash attention (swapped QK^T) + W_o + residual, all MFMA.
// grid 256 = 16 b x 16 q-tiles; 512 thr = 8 waves x 32 q.
// Critical-path fixes vs R4: v_permlane32_swap_b32 replaces ds_bpermute
// shuffles (one swap yields BOTH PV A-fragment words); next-kt fragments
// prefetched into registers; no divergent masked loads (qf zeros alone
// null the k=8..15 contribution).
// -------------------------------------------------------------------------
__global__ __launch_bounds__(512, 2) void attn_kernel(
    const float* __restrict__ x,  const ushort* __restrict__ thetaT,
    const ushort* __restrict__ kv, const float* __restrict__ Wo,
    const float* __restrict__ gammap, float* __restrict__ out)
{
    __shared__ __align__(16) char smem[40960];
    ushort* phiT_s  = (ushort*)smem;            // 8 KB   [512 key][8 c]
    ushort* gfrag_s = (ushort*)(smem + 8192);   // 32 KB  [32 T][64 lane][8 j]

    const int t  = threadIdx.x;
    const int w  = t >> 6, l = t & 63, ql = l & 31, h = l >> 5;
    const int b  = blockIdx.x >> 4, qt = blockIdx.x & 15;
    const int nq = qt*256 + w*32 + ql;          // this lane's query pixel
    const ushort* kvb = kv + (size_t)b * 40960;

    // Q fragment (B-operand): k 0-7 real theta, k 8-15 zero (kills need to
    // mask the phi A-operand: A*0 contributes nothing).
    U4B8 qv;
    qv.b = *(const bf16x8*)(thetaT + ((size_t)(b*NPIX + nq))*8);
    {
        const uint qm = h ? 0u : 0xFFFFFFFFu;
#pragma unroll
        for (int i = 0; i < 4; ++i) qv.u[i] &= qm;
    }

    f32x16 acc = zero16();
    float lp = 0.0f;

    for (int H = 0; H < 2; ++H) {
        __syncthreads();
        {   // stage 512 keys: phiT half (8 KB) + g_frag half (32 KB)
            const uint4* sp = (const uint4*)(kvb + H*4096);
            ((uint4*)phiT_s)[t] = sp[t];
            const uint4* sg = (const uint4*)(kvb + 8192 + H*16384);
            uint4* dg = (uint4*)gfrag_s;
#pragma unroll
            for (int i = 0; i < 4; ++i) dg[t + i*512] = sg[t + i*512];
        }
        __syncthreads();

        // register prefetch pipeline over kt
        bf16x8 af = *(const bf16x8*)(phiT_s + (0*32 + ql)*8);
        bf16x8 g0 = *(const bf16x8*)(gfrag_s + ((0*2 + 0)*64 + l)*8);
        bf16x8 g1 = *(const bf16x8*)(gfrag_s + ((0*2 + 1)*64 + l)*8);

#pragma unroll 4
        for (int kt = 0; kt < 16; ++kt) {
            const int ktn = (kt + 1) & 15;      // kt=15 prefetch is dead, harmless
            const bf16x8 afn = *(const bf16x8*)(phiT_s + (ktn*32 + ql)*8);
            const bf16x8 g0n = *(const bf16x8*)(gfrag_s + ((ktn*2 + 0)*64 + l)*8);
            const bf16x8 g1n = *(const bf16x8*)(gfrag_s + ((ktn*2 + 1)*64 + l)*8);

            // S^T[key, q]
            f32x16 st = __builtin_amdgcn_mfma_f32_32x32x16_bf16(af, qv.b, zero16(), 0,0,0);
            f32x16 P;
#pragma unroll
            for (int r = 0; r < 16; ++r) P[r] = __builtin_exp2f(st[r]);
            lp += (((P[0]+P[1])+(P[2]+P[3])) + ((P[4]+P[5])+(P[6]+P[7])))
                + (((P[8]+P[9])+(P[10]+P[11])) + ((P[12]+P[13])+(P[14]+P[15])));

#pragma unroll
            for (int ks = 0; ks < 2; ++ks) {
                const int bb = ks*8;
                // own keys (reg r, half h): key = (r&3) + 8*((r>>2)&1) + 16*(r>>3) + 4h
                uint X01 = cvtpk(P[bb+0], P[bb+1]);
                uint X23 = cvtpk(P[bb+2], P[bb+3]);
                uint Y01 = cvtpk(P[bb+4], P[bb+5]);
                uint Y23 = cvtpk(P[bb+6], P[bb+7]);
                // swap upper(X) with lower(Y): X={Xlo,Ylo}, Y={Xhi,Yhi} -> the
                // two A-fragment words for q=lane&31, k=8h+j.
                asm("v_permlane32_swap_b32 %0, %1" : "+v"(X01), "+v"(Y01));
                asm("v_permlane32_swap_b32 %0, %1" : "+v"(X23), "+v"(Y23));
                U4B8 pa;
                pa.u[0] = X01; pa.u[1] = X23; pa.u[2] = Y01; pa.u[3] = Y23;
                acc = __builtin_amdgcn_mfma_f32_32x32x16_bf16(
                          pa.b, ks ? g1 : g0, acc, 0,0,0);
            }
            af = afn; g0 = g0n; g1 = g1n;
        }
    }

    // softmax denominator: lane pair (ql, ql+32) halves combined via permlane
    float la = lp, lb = lp;
    asm("v_permlane32_swap_b32 %0, %1" : "+v"(la), "+v"(lb));
    const float rinv = 1.0f / (la + lb);

    // transpose av through LDS (aliases staging; all K-loop reads done)
    __syncthreads();
    float* avw = (float*)smem + w * (32*33);
#pragma unroll
    for (int r = 0; r < 16; ++r) {
        const int crow = (r&3) + 8*(r>>2) + 4*h;     // q row
        avw[crow*33 + ql] = acc[r];                  // [q][gc]
    }
    __syncthreads();

    // epilogue: o^T[oc, q] = Wo[oc, gc] x (av[q, gc]/l)
    bf16x8 avB[2];
#pragma unroll
    for (int s = 0; s < 2; ++s) {
        float v[8];
#pragma unroll
        for (int j = 0; j < 8; ++j) v[j] = avw[ql*33 + s*16 + h*8 + j] * rinv;
        U4B8 cv;
        cv.u[0]=cvtpk(v[0],v[1]); cv.u[1]=cvtpk(v[2],v[3]);
        cv.u[2]=cvtpk(v[4],v[5]); cv.u[3]=cvtpk(v[6],v[7]);
        avB[s] = cv.b;
    }
    const float gamma = gammap[0];
    const float* xb = x  + (size_t)b*64*NPIX + nq;
    float*       ob = out + (size_t)b*64*NPIX + nq;
#pragma unroll
    for (int T = 0; T < 2; ++T) {
        f32x16 oacc = zero16();
#pragma unroll
        for (int s = 0; s < 2; ++s) {
            const float* wrow = Wo + (T*32 + ql)*32 + s*16 + h*8;
            U4B8 cv;
            cv.u[0]=cvtpk(wrow[0],wrow[1]); cv.u[1]=cvtpk(wrow[2],wrow[3]);
            cv.u[2]=cvtpk(wrow[4],wrow[5]); cv.u[3]=cvtpk(wrow[6],wrow[7]);
            oacc = __builtin_amdgcn_mfma_f32_32x32x16_bf16(cv.b, avB[s], oacc, 0,0,0);
        }
#pragma unroll
        for (int r = 0; r < 16; ++r) {
            const int oc = T*32 + (r&3) + 8*(r>>2) + 4*h;
            ob[(size_t)oc*NPIX] = gamma * oacc[r] + xb[(size_t)oc*NPIX];
        }
    }
}

extern "C" void kernel_launch(void* const* d_in, const int* in_sizes, int n_in,
                              void* d_out, int out_size, void* d_ws, size_t ws_size,
                              hipStream_t stream) {
    const float* x     = (const float*)d_in[0];
    const float* Wth   = (const float*)d_in[1];
    const float* Wph   = (const float*)d_in[2];
    const float* Wg    = (const float*)d_in[3];
    const float* Wo    = (const float*)d_in[4];
    const float* gamma = (const float*)d_in[5];
    float* out = (float*)d_out;

    ushort* thetaT = (ushort*)d_ws;                // 16*4096*8 ushort = 1 MB
    ushort* kv     = thetaT + (size_t)NB*NPIX*8;   // 16 * 40960 ushort

    proj_kernel<<<NB*32, 256, 0, stream>>>(x, Wth, Wph, Wg, thetaT, kv);
    attn_kernel<<<NB*16, 512, 0, stream>>>(x, thetaT, kv, Wo, gamma, out);
}